// Round 4
// baseline (218.722 us; speedup 1.0000x reference)
//
#include <hip/hip_runtime.h>
#include <cmath>

// ---------------- problem constants ----------------
#define SNUM 6
#define CNUM 128
#define HF 56
#define WF 100
#define HW (HF*WF)          // 5600
#define ZN 128
#define YN 8
#define XN 128
#define NVOX (ZN*YN*XN)     // 131072

typedef __attribute__((ext_vector_type(8))) short bf16x8;
typedef __attribute__((ext_vector_type(4))) float f32x4;
typedef __attribute__((ext_vector_type(4))) int   i32x4;

__device__ __forceinline__ unsigned short f2bf(float f) {
    unsigned u = __builtin_bit_cast(unsigned, f);
    unsigned r = (u + 0x7FFFu + ((u >> 16) & 1u)) >> 16;   // RNE
    return (unsigned short)r;
}
__device__ __forceinline__ float bf2f(unsigned short h) {
    unsigned u = (unsigned)h << 16;
    return __builtin_bit_cast(float, u);
}

// ---------------- setup: per-camera matrices ----------------
__global__ void k_setup(const float* __restrict__ intrins,
                        const float* __restrict__ rots,
                        const float* __restrict__ trans,
                        float* __restrict__ mats) {
    int s = threadIdx.x;
    if (s >= SNUM) return;
    float R0[9], Rs[9], t0[3], ts[3];
    for (int i = 0; i < 9; ++i) { R0[i] = rots[i]; Rs[i] = rots[s*9 + i]; }
    for (int i = 0; i < 3; ++i) { t0[i] = trans[i]; ts[i] = trans[s*3 + i]; }
    float M[3][4];
    float d0 = t0[0]-ts[0], d1 = t0[1]-ts[1], d2 = t0[2]-ts[2];
    for (int i = 0; i < 3; ++i) {
        for (int j = 0; j < 3; ++j)
            M[i][j] = Rs[0*3+i]*R0[0*3+j] + Rs[1*3+i]*R0[1*3+j] + Rs[2*3+i]*R0[2*3+j];
        M[i][3] = Rs[0*3+i]*d0 + Rs[1*3+i]*d1 + Rs[2*3+i]*d2;
    }
    const float sx = (float)WF/800.0f, sy = (float)HF/448.0f;
    float fx = intrins[s*16 + 0]*sx, fy = intrins[s*16 + 5]*sy;
    float cx = intrins[s*16 + 2]*sx, cy = intrins[s*16 + 6]*sy;
    float* o = mats + s*24;
    for (int j = 0; j < 4; ++j) {
        o[0*4+j]      = M[0][j];
        o[1*4+j]      = M[1][j];
        o[2*4+j]      = M[2][j];
        o[12 + 0*4+j] = fx*M[0][j] + cx*M[2][j];
        o[12 + 1*4+j] = fy*M[1][j] + cy*M[2][j];
        o[12 + 2*4+j] = M[2][j];
    }
}

// ---------------- transpose cam_feat (S,C,HW) f32 -> featT (S,HW,C) bf16 -------
__global__ __launch_bounds__(256) void k_tfeat(const float* __restrict__ cf,
                                               unsigned short* __restrict__ featT) {
    __shared__ float t[32][33];
    int s = blockIdx.z;
    int p0 = blockIdx.x * 32, c0 = blockIdx.y * 32;
    int tx = threadIdx.x, ty = threadIdx.y;   // 32 x 8
#pragma unroll
    for (int k = 0; k < 4; ++k) {
        int r = ty + k*8;
        t[r][tx] = cf[((size_t)s*CNUM + c0 + r)*HW + p0 + tx];
    }
    __syncthreads();
#pragma unroll
    for (int k = 0; k < 4; ++k) {
        int r = ty + k*8;
        featT[((size_t)s*HW + p0 + r)*CNUM + c0 + tx] = f2bf(t[tx][r]);
    }
}

// ---------------- per-voxel projection -> (ux,uy) per camera ----------------
__global__ __launch_bounds__(256) void k_geo(const float* __restrict__ mats,
                                             float* __restrict__ uv) {
#pragma clang fp contract(off)
    int n = blockIdx.x * 256 + threadIdx.x;
    int zi = n >> 10, yi = (n >> 7) & 7, xi = n & 127;
    float xr = -49.609375f + (float)xi * 0.78125f;
    float yr = (-4.9f + 0.625f) + (float)yi * 1.25f;
    float zr = -49.609375f + (float)zi * 0.78125f;
#pragma unroll
    for (int s = 0; s < SNUM; ++s) {
        const float* m = mats + s*24;
        float zc = m[8]*xr  + m[9]*yr  + m[10]*zr + m[11];
        float ph = m[12]*xr + m[13]*yr + m[14]*zr + m[15];
        float qh = m[16]*xr + m[17]*yr + m[18]*zr + m[19];
        float denom = fmaxf(zc, 1e-6f);
        float px = ph / denom, py = qh / denom;
        bool valid = (px > -0.5f) & (px < (float)WF - 0.5f) &
                     (py > -0.5f) & (py < (float)HF - 0.5f) & (zc > 0.0f);
        float ux = -10000.0f, uy = -10000.0f;
        if (valid) {
            float gx = 2.0f*px/((float)WF - 1.0f) - 1.0f;
            float gy = 2.0f*py/((float)HF - 1.0f) - 1.0f;
            gx = fminf(fmaxf(gx, -2.0f), 2.0f);
            gy = fminf(fmaxf(gy, -2.0f), 2.0f);
            ux = ((gx + 1.0f)*(float)WF - 1.0f)*0.5f;
            uy = ((gy + 1.0f)*(float)HF - 1.0f)*0.5f;
        }
        uv[(n*SNUM + s)*2]     = ux;
        uv[(n*SNUM + s)*2 + 1] = uy;
    }
}

// ---------------- bilinear sample + masked camera mean -> bevin bf16 [z][x][ci] ----
__global__ __launch_bounds__(256) void k_sample(const unsigned short* __restrict__ featT,
                                                const float* __restrict__ uv,
                                                unsigned short* __restrict__ bevin) {
#pragma clang fp contract(off)
    __shared__ float xch[16][132];        // [vs = y*2+xs][c]
    const int tid = threadIdx.x;
    const int b = blockIdx.x;             // 8192 = 128 z * 64 x-pairs
    const int z = b >> 6, x0 = (b & 63) * 2;
    const int cl = tid & 15, vs = tid >> 4;
    const int y = vs >> 1, xs = vs & 1;
    const int n = z*1024 + y*128 + x0 + xs;
    const bf16x8 zz8 = {0,0,0,0,0,0,0,0};
    float sum[8], cnt[8];
#pragma unroll
    for (int k = 0; k < 8; ++k) { sum[k] = 0.0f; cnt[k] = 0.0f; }
    for (int s = 0; s < SNUM; ++s) {
        float2 u = ((const float2*)uv)[n*SNUM + s];
        if (u.x < -999.0f) continue;
        float x0f = floorf(u.x), y0f = floorf(u.y);
        float wx = u.x - x0f, wy = u.y - y0f;
        int ix = (int)x0f, iy = (int)y0f;
        float w00 = (1.0f-wx)*(1.0f-wy), w10 = wx*(1.0f-wy);
        float w01 = (1.0f-wx)*wy,        w11 = wx*wy;
        bool bx0 = (ix >= 0) & (ix < WF);
        bool bx1 = (ix >= -1) & (ix < WF-1);
        bool by0 = (iy >= 0) & (iy < HF);
        bool by1 = (iy >= -1) & (iy < HF-1);
        bool c00 = bx0 & by0, c10 = bx1 & by0, c01 = bx0 & by1, c11 = bx1 & by1;
        const unsigned short* fb = featT + (size_t)s * (HW*CNUM) + cl*8;
        long r0 = (long)(iy*WF + ix) * CNUM;
        bf16x8 v00 = c00 ? *(const bf16x8*)(fb + r0)                 : zz8;
        bf16x8 v10 = c10 ? *(const bf16x8*)(fb + r0 + CNUM)          : zz8;
        bf16x8 v01 = c01 ? *(const bf16x8*)(fb + r0 + WF*CNUM)       : zz8;
        bf16x8 v11 = c11 ? *(const bf16x8*)(fb + r0 + WF*CNUM + CNUM): zz8;
#pragma unroll
        for (int k = 0; k < 8; ++k) {
            float v = 0.0f;
            v = v + w00 * bf2f((unsigned short)v00[k]);
            v = v + w10 * bf2f((unsigned short)v10[k]);
            v = v + w01 * bf2f((unsigned short)v01[k]);
            v = v + w11 * bf2f((unsigned short)v11[k]);
            sum[k] += v;
            cnt[k] += (v != 0.0f) ? 1.0f : 0.0f;
        }
    }
#pragma unroll
    for (int k = 0; k < 8; ++k)
        xch[vs][cl*8 + k] = sum[k] / (1e-6f + cnt[k]);
    __syncthreads();
    // pack to bf16: element e = c*8+y at bevin[(z*128 + x0+xs)*1024 + e]
#pragma unroll
    for (int j = 0; j < 4; ++j) {
        int m = tid + j*256;              // uint index in [0,1024)
        int xs2 = m >> 9;
        int r = m & 511;                  // elements 2r, 2r+1
        int c = (2*r) >> 3, y0 = (2*r) & 7;
        float v0 = xch[y0*2 + xs2][c];
        float v1 = xch[(y0+1)*2 + xs2][c];
        unsigned pk = (unsigned)f2bf(v0) | ((unsigned)f2bf(v1) << 16);
        ((unsigned*)bevin)[(size_t)(z*128 + x0 + xs2)*512 + r] = pk;
    }
}

// ---------------- weight prep: conv_w [co][ci][3][3] f32 -> w2 [tap][co][ci] bf16 ----
__global__ __launch_bounds__(256) void k_wprep(const float* __restrict__ w,
                                               unsigned short* __restrict__ w2) {
    int i = blockIdx.x*256 + threadIdx.x;     // over 9*128*1024
    if (i >= 9*128*1024) return;
    int ci = i & 1023; int rest = i >> 10; int co = rest & 127; int tap = rest >> 7;
    w2[i] = f2bf(w[((size_t)co*1024 + ci)*9 + tap]);
}

// ---------------- MFMA implicit-GEMM conv 3x3 ----------------
// grid (128 z, 4 co-quarter) = 512 blocks -> 2 blocks/CU, 2 waves/SIMD.
// block 256 = 4 waves (x-groups), wave tile 32co x 32x. A regs dbuf, B LDS dbuf.
__global__ __launch_bounds__(256, 2) void k_conv_mfma(
        const unsigned short* __restrict__ bevin,   // [z][x][1024] bf16
        const unsigned short* __restrict__ w2,      // [tap][co][1024] bf16
        float* __restrict__ out) {
    __shared__ unsigned short lds[2][12*130*8];     // [buf][(zr*4+kg)*130 + xpad][8ci]
    const int tid  = threadIdx.x;
    const int z0   = blockIdx.x;
    const int coq  = blockIdx.y;
    const int lane = tid & 63, wxg = tid >> 6;      // wave x-group 0..3
    const int co_base = coq*32;
    const int l15 = lane & 15, lhi = lane >> 4;

    // zero x-padding columns (xpad=0 and xpad=129) once; never overwritten
    if (tid < 48) {
        int bf = tid & 1, q = tid >> 1;      // q in [0,24)
        int row = q >> 1, side = q & 1;      // row in [0,12)
        *(i32x4*)&lds[bf][(row*130 + side*129)*8] = i32x4{0,0,0,0};
    }

    f32x4 acc[2][2];
#pragma unroll
    for (int f = 0; f < 2; ++f)
#pragma unroll
        for (int nf = 0; nf < 2; ++nf) acc[f][nf] = f32x4{0.f,0.f,0.f,0.f};

    const unsigned short* aw0 = w2 + ((size_t)(co_base      + l15))*1024 + lhi*8;
    const unsigned short* aw1 = w2 + ((size_t)(co_base + 16 + l15))*1024 + lhi*8;

    bf16x8 afr0[18], afr1[18];
    i32x4 pre[6];
    bool  pv[6];

#define A_LOAD(DST, CI0)                                                       \
    {                                                                          \
        _Pragma("unroll")                                                      \
        for (int t = 0; t < 9; ++t) {                                          \
            DST[t*2]   = *(const bf16x8*)(aw0 + (size_t)t*131072 + (CI0));     \
            DST[t*2+1] = *(const bf16x8*)(aw1 + (size_t)t*131072 + (CI0));     \
        }                                                                      \
    }
#define B_LOAD(CI0)                                                            \
    {                                                                          \
        _Pragma("unroll")                                                      \
        for (int j = 0; j < 6; ++j) {                                          \
            int i  = tid + j*256;                                              \
            int kg = i & 3, x = (i >> 2) & 127, zr = i >> 9;                   \
            int zz = z0 - 1 + zr;                                              \
            pv[j] = ((unsigned)zz < 128u);                                     \
            if (pv[j])                                                         \
                pre[j] = *(const i32x4*)&bevin[((size_t)(zz*128 + x))*1024 + (CI0) + kg*8]; \
        }                                                                      \
    }
#define B_WRITE(BUF)                                                           \
    {                                                                          \
        _Pragma("unroll")                                                      \
        for (int j = 0; j < 6; ++j) {                                          \
            int i  = tid + j*256;                                              \
            int kg = i & 3, x = (i >> 2) & 127, zr = i >> 9;                   \
            if (pv[j])                                                         \
                *(i32x4*)&lds[BUF][(((zr*4 + kg)*130) + 1 + x)*8] = pre[j];    \
        }                                                                      \
    }
#define COMPUTE(BUF, AFR)                                                      \
    {                                                                          \
        _Pragma("unroll")                                                      \
        for (int dz = 0; dz < 3; ++dz) {                                       \
            if ((unsigned)(z0 - 1 + dz) < 128u) {                              \
                _Pragma("unroll")                                              \
                for (int dx = 0; dx < 3; ++dx) {                               \
                    bf16x8 a0 = AFR[(dz*3+dx)*2];                              \
                    bf16x8 a1 = AFR[(dz*3+dx)*2+1];                            \
                    _Pragma("unroll")                                          \
                    for (int nf = 0; nf < 2; ++nf) {                           \
                        int xp = wxg*32 + nf*16 + l15 + dx;                    \
                        bf16x8 bfr = *(const bf16x8*)&lds[BUF][(((dz*4 + lhi)*130) + xp)*8]; \
                        acc[0][nf] = __builtin_amdgcn_mfma_f32_16x16x32_bf16(a0, bfr, acc[0][nf], 0, 0, 0); \
                        acc[1][nf] = __builtin_amdgcn_mfma_f32_16x16x32_bf16(a1, bfr, acc[1][nf], 0, 0, 0); \
                    }                                                          \
                }                                                              \
            }                                                                  \
        }                                                                      \
    }

    // prologue: chunk 0 -> buf0 / afr0
    B_LOAD(0);
    A_LOAD(afr0, 0);
    __syncthreads();     // pad zero-fill visible
    B_WRITE(0);
    __syncthreads();

    for (int cc = 0; cc < 16; ++cc) {
        const int ci0 = cc*64;
        // --- chunk cc*2 : compute buf0/afr0, prefetch chunk cc*2+1 -> buf1/afr1
        B_LOAD(ci0 + 32);
        A_LOAD(afr1, ci0 + 32);
        COMPUTE(0, afr0);
        B_WRITE(1);
        __syncthreads();
        // --- chunk cc*2+1 : compute buf1/afr1, prefetch chunk cc*2+2 -> buf0/afr0
        if (cc < 15) {
            B_LOAD(ci0 + 64);
            A_LOAD(afr0, ci0 + 64);
        }
        COMPUTE(1, afr1);
        if (cc < 15) {
            B_WRITE(0);
            __syncthreads();
        }
    }

    // epilogue: D row=(lhi*4+r) -> co, col=l15 -> x
#pragma unroll
    for (int f = 0; f < 2; ++f)
#pragma unroll
        for (int nf = 0; nf < 2; ++nf)
#pragma unroll
            for (int r = 0; r < 4; ++r) {
                int co = co_base + f*16 + lhi*4 + r;
                out[(size_t)co*16384 + z0*128 + wxg*32 + nf*16 + l15] = acc[f][nf][r];
            }
#undef A_LOAD
#undef B_LOAD
#undef B_WRITE
#undef COMPUTE
}

// ---------------- instance-norm stats ----------------
__global__ __launch_bounds__(256) void k_instnorm_stats(const float* __restrict__ out,
                                                        float* __restrict__ stats) {
    __shared__ float r1[256], r2[256];
    int co = blockIdx.x, tid = threadIdx.x;
    const float* p = out + (size_t)co*16384;
    float s1 = 0.0f, s2 = 0.0f;
    for (int i = tid; i < 16384; i += 256) { float v = p[i]; s1 += v; s2 += v*v; }
    r1[tid] = s1; r2[tid] = s2;
    __syncthreads();
    for (int off = 128; off > 0; off >>= 1) {
        if (tid < off) { r1[tid] += r1[tid+off]; r2[tid] += r2[tid+off]; }
        __syncthreads();
    }
    if (tid == 0) {
        float mean = r1[0] * (1.0f/16384.0f);
        float var  = r2[0] * (1.0f/16384.0f) - mean*mean;
        stats[co*2]   = mean;
        stats[co*2+1] = rsqrtf(var + 1e-5f);
    }
}

// ---------------- normalize + exact GELU (in place) ----------------
__global__ __launch_bounds__(256) void k_gelu(float* __restrict__ out,
                                              const float* __restrict__ stats) {
    int i = blockIdx.x*256 + threadIdx.x;
    int co = i >> 14;
    float v = out[i];
    float r = (v - stats[co*2]) * stats[co*2+1];
    out[i] = 0.5f * r * (1.0f + erff(r * 0.70710678118654752f));
}

extern "C" void kernel_launch(void* const* d_in, const int* in_sizes, int n_in,
                              void* d_out, int out_size, void* d_ws, size_t ws_size,
                              hipStream_t stream) {
    const float* cam_feat = (const float*)d_in[0];
    const float* intrins  = (const float*)d_in[1];
    const float* rots     = (const float*)d_in[2];
    const float* trans    = (const float*)d_in[3];
    const float* conv_w   = (const float*)d_in[4];
    float* out = (float*)d_out;
    float* ws  = (float*)d_ws;

    float* mats  = ws;                                          // 160 f
    float* uv    = ws + 160;                                    // NVOX*12 f
    unsigned short* featT = (unsigned short*)(uv + (size_t)NVOX*12);   // 4,300,800 bf16
    unsigned short* bevin = featT + (size_t)SNUM*HW*CNUM;       // 16,777,216 bf16
    unsigned short* w2    = bevin + (size_t)16384*1024;         // 1,179,648 bf16
    float* stats = (float*)(w2 + 9*128*1024);                   // 256 f
    // total ~50.8 MB

    hipLaunchKernelGGL(k_setup, dim3(1), dim3(64), 0, stream, intrins, rots, trans, mats);
    hipLaunchKernelGGL(k_tfeat, dim3(HW/32, CNUM/32, SNUM), dim3(32,8), 0, stream, cam_feat, featT);
    hipLaunchKernelGGL(k_geo, dim3(NVOX/256), dim3(256), 0, stream, mats, uv);
    hipLaunchKernelGGL(k_wprep, dim3((9*128*1024 + 255)/256), dim3(256), 0, stream, conv_w, w2);
    hipLaunchKernelGGL(k_sample, dim3(8192), dim3(256), 0, stream, featT, uv, bevin);
    hipLaunchKernelGGL(k_conv_mfma, dim3(128, 4), dim3(256), 0, stream, bevin, w2, out);
    hipLaunchKernelGGL(k_instnorm_stats, dim3(128), dim3(256), 0, stream, out, stats);
    hipLaunchKernelGGL(k_gelu, dim3(8192), dim3(256), 0, stream, out, stats);
}

// Round 5
// 210.528 us; speedup vs baseline: 1.0389x; 1.0389x over previous
//
#include <hip/hip_runtime.h>
#include <cmath>

// ---------------- problem constants ----------------
#define SNUM 6
#define CNUM 128
#define HF 56
#define WF 100
#define HW (HF*WF)          // 5600
#define ZN 128
#define YN 8
#define XN 128
#define NVOX (ZN*YN*XN)     // 131072

typedef __attribute__((ext_vector_type(8))) short bf16x8;
typedef __attribute__((ext_vector_type(4))) float f32x4;
typedef __attribute__((ext_vector_type(4))) int   i32x4;

__device__ __forceinline__ unsigned short f2bf(float f) {
    unsigned u = __builtin_bit_cast(unsigned, f);
    unsigned r = (u + 0x7FFFu + ((u >> 16) & 1u)) >> 16;   // RNE
    return (unsigned short)r;
}
__device__ __forceinline__ float bf2f(unsigned short h) {
    unsigned u = (unsigned)h << 16;
    return __builtin_bit_cast(float, u);
}

// ---------------- setup: per-camera matrices ----------------
__global__ void k_setup(const float* __restrict__ intrins,
                        const float* __restrict__ rots,
                        const float* __restrict__ trans,
                        float* __restrict__ mats) {
    int s = threadIdx.x;
    if (s >= SNUM) return;
    float R0[9], Rs[9], t0[3], ts[3];
    for (int i = 0; i < 9; ++i) { R0[i] = rots[i]; Rs[i] = rots[s*9 + i]; }
    for (int i = 0; i < 3; ++i) { t0[i] = trans[i]; ts[i] = trans[s*3 + i]; }
    float M[3][4];
    float d0 = t0[0]-ts[0], d1 = t0[1]-ts[1], d2 = t0[2]-ts[2];
    for (int i = 0; i < 3; ++i) {
        for (int j = 0; j < 3; ++j)
            M[i][j] = Rs[0*3+i]*R0[0*3+j] + Rs[1*3+i]*R0[1*3+j] + Rs[2*3+i]*R0[2*3+j];
        M[i][3] = Rs[0*3+i]*d0 + Rs[1*3+i]*d1 + Rs[2*3+i]*d2;
    }
    const float sx = (float)WF/800.0f, sy = (float)HF/448.0f;
    float fx = intrins[s*16 + 0]*sx, fy = intrins[s*16 + 5]*sy;
    float cx = intrins[s*16 + 2]*sx, cy = intrins[s*16 + 6]*sy;
    float* o = mats + s*24;
    for (int j = 0; j < 4; ++j) {
        o[0*4+j]      = M[0][j];
        o[1*4+j]      = M[1][j];
        o[2*4+j]      = M[2][j];
        o[12 + 0*4+j] = fx*M[0][j] + cx*M[2][j];
        o[12 + 1*4+j] = fy*M[1][j] + cy*M[2][j];
        o[12 + 2*4+j] = M[2][j];
    }
}

// ---------------- transpose cam_feat (S,C,HW) f32 -> featT (S,HW,C) bf16 -------
__global__ __launch_bounds__(256) void k_tfeat(const float* __restrict__ cf,
                                               unsigned short* __restrict__ featT) {
    __shared__ float t[32][33];
    int s = blockIdx.z;
    int p0 = blockIdx.x * 32, c0 = blockIdx.y * 32;
    int tx = threadIdx.x, ty = threadIdx.y;   // 32 x 8
#pragma unroll
    for (int k = 0; k < 4; ++k) {
        int r = ty + k*8;
        t[r][tx] = cf[((size_t)s*CNUM + c0 + r)*HW + p0 + tx];
    }
    __syncthreads();
#pragma unroll
    for (int k = 0; k < 4; ++k) {
        int r = ty + k*8;
        featT[((size_t)s*HW + p0 + r)*CNUM + c0 + tx] = f2bf(t[tx][r]);
    }
}

// ---------------- per-voxel projection -> (ux,uy) per camera ----------------
__global__ __launch_bounds__(256) void k_geo(const float* __restrict__ mats,
                                             float* __restrict__ uv) {
#pragma clang fp contract(off)
    int n = blockIdx.x * 256 + threadIdx.x;
    int zi = n >> 10, yi = (n >> 7) & 7, xi = n & 127;
    float xr = -49.609375f + (float)xi * 0.78125f;
    float yr = (-4.9f + 0.625f) + (float)yi * 1.25f;
    float zr = -49.609375f + (float)zi * 0.78125f;
#pragma unroll
    for (int s = 0; s < SNUM; ++s) {
        const float* m = mats + s*24;
        float zc = m[8]*xr  + m[9]*yr  + m[10]*zr + m[11];
        float ph = m[12]*xr + m[13]*yr + m[14]*zr + m[15];
        float qh = m[16]*xr + m[17]*yr + m[18]*zr + m[19];
        float denom = fmaxf(zc, 1e-6f);
        float px = ph / denom, py = qh / denom;
        bool valid = (px > -0.5f) & (px < (float)WF - 0.5f) &
                     (py > -0.5f) & (py < (float)HF - 0.5f) & (zc > 0.0f);
        float ux = -10000.0f, uy = -10000.0f;
        if (valid) {
            float gx = 2.0f*px/((float)WF - 1.0f) - 1.0f;
            float gy = 2.0f*py/((float)HF - 1.0f) - 1.0f;
            gx = fminf(fmaxf(gx, -2.0f), 2.0f);
            gy = fminf(fmaxf(gy, -2.0f), 2.0f);
            ux = ((gx + 1.0f)*(float)WF - 1.0f)*0.5f;
            uy = ((gy + 1.0f)*(float)HF - 1.0f)*0.5f;
        }
        uv[(n*SNUM + s)*2]     = ux;
        uv[(n*SNUM + s)*2 + 1] = uy;
    }
}

// ---------------- bilinear sample + masked camera mean -> bevin bf16 [z][x][ci] ----
__global__ __launch_bounds__(256) void k_sample(const unsigned short* __restrict__ featT,
                                                const float* __restrict__ uv,
                                                unsigned short* __restrict__ bevin) {
#pragma clang fp contract(off)
    __shared__ float xch[16][132];        // [vs = y*2+xs][c]
    const int tid = threadIdx.x;
    const int b = blockIdx.x;             // 8192 = 128 z * 64 x-pairs
    const int z = b >> 6, x0 = (b & 63) * 2;
    const int cl = tid & 15, vs = tid >> 4;
    const int y = vs >> 1, xs = vs & 1;
    const int n = z*1024 + y*128 + x0 + xs;
    const bf16x8 zz8 = {0,0,0,0,0,0,0,0};
    float sum[8], cnt[8];
#pragma unroll
    for (int k = 0; k < 8; ++k) { sum[k] = 0.0f; cnt[k] = 0.0f; }
    for (int s = 0; s < SNUM; ++s) {
        float2 u = ((const float2*)uv)[n*SNUM + s];
        if (u.x < -999.0f) continue;
        float x0f = floorf(u.x), y0f = floorf(u.y);
        float wx = u.x - x0f, wy = u.y - y0f;
        int ix = (int)x0f, iy = (int)y0f;
        float w00 = (1.0f-wx)*(1.0f-wy), w10 = wx*(1.0f-wy);
        float w01 = (1.0f-wx)*wy,        w11 = wx*wy;
        bool bx0 = (ix >= 0) & (ix < WF);
        bool bx1 = (ix >= -1) & (ix < WF-1);
        bool by0 = (iy >= 0) & (iy < HF);
        bool by1 = (iy >= -1) & (iy < HF-1);
        bool c00 = bx0 & by0, c10 = bx1 & by0, c01 = bx0 & by1, c11 = bx1 & by1;
        const unsigned short* fb = featT + (size_t)s * (HW*CNUM) + cl*8;
        long r0 = (long)(iy*WF + ix) * CNUM;
        bf16x8 v00 = c00 ? *(const bf16x8*)(fb + r0)                 : zz8;
        bf16x8 v10 = c10 ? *(const bf16x8*)(fb + r0 + CNUM)          : zz8;
        bf16x8 v01 = c01 ? *(const bf16x8*)(fb + r0 + WF*CNUM)       : zz8;
        bf16x8 v11 = c11 ? *(const bf16x8*)(fb + r0 + WF*CNUM + CNUM): zz8;
#pragma unroll
        for (int k = 0; k < 8; ++k) {
            float v = 0.0f;
            v = v + w00 * bf2f((unsigned short)v00[k]);
            v = v + w10 * bf2f((unsigned short)v10[k]);
            v = v + w01 * bf2f((unsigned short)v01[k]);
            v = v + w11 * bf2f((unsigned short)v11[k]);
            sum[k] += v;
            cnt[k] += (v != 0.0f) ? 1.0f : 0.0f;
        }
    }
#pragma unroll
    for (int k = 0; k < 8; ++k)
        xch[vs][cl*8 + k] = sum[k] / (1e-6f + cnt[k]);
    __syncthreads();
    // pack to bf16: element e = c*8+y at bevin[(z*128 + x0+xs)*1024 + e]
#pragma unroll
    for (int j = 0; j < 4; ++j) {
        int m = tid + j*256;              // uint index in [0,1024)
        int xs2 = m >> 9;
        int r = m & 511;                  // elements 2r, 2r+1
        int c = (2*r) >> 3, y0 = (2*r) & 7;
        float v0 = xch[y0*2 + xs2][c];
        float v1 = xch[(y0+1)*2 + xs2][c];
        unsigned pk = (unsigned)f2bf(v0) | ((unsigned)f2bf(v1) << 16);
        ((unsigned*)bevin)[(size_t)(z*128 + x0 + xs2)*512 + r] = pk;
    }
}

// ---------------- weight prep: conv_w [co][ci][3][3] f32 -> w2 [tap][co][ci] bf16 ----
__global__ __launch_bounds__(256) void k_wprep(const float* __restrict__ w,
                                               unsigned short* __restrict__ w2) {
    int i = blockIdx.x*256 + threadIdx.x;     // over 9*128*1024
    if (i >= 9*128*1024) return;
    int ci = i & 1023; int rest = i >> 10; int co = rest & 127; int tap = rest >> 7;
    w2[i] = f2bf(w[((size_t)co*1024 + ci)*9 + tap]);
}

// ---------------- MFMA implicit-GEMM conv 3x3 ----------------
// grid (128 z, coh*2+xh) = 512 blocks -> 2 blocks/CU with INDEPENDENT barriers.
// block = 64co x 64x: 4 waves (2 co x 2 x), wave tile 32co x 32x.
// Per-CU LDS traffic identical to round-3 config; A regs dbuf; B LDS dbuf.
__global__ __launch_bounds__(256, 2) void k_conv_mfma(
        const unsigned short* __restrict__ bevin,   // [z][x][1024] bf16
        const unsigned short* __restrict__ w2,      // [tap][co][1024] bf16
        float* __restrict__ out) {
    __shared__ unsigned short lds[2][12*66*8];      // [buf][(zr*4+kg)*66 + xpad][8ci]
    const int tid  = threadIdx.x;
    const int z0   = blockIdx.x;
    const int coh  = blockIdx.y >> 1;               // co half: 0,1
    const int xh   = blockIdx.y & 1;                // x half: 0,1
    const int lane = tid & 63, wid = tid >> 6;
    const int wr = wid >> 1, xw = wid & 1;          // wave co-row, wave x-col
    const int co_base = coh*64 + wr*32;
    const int l15 = lane & 15, lhi = lane >> 4;

    // zero the out-of-range halo column once (xh=0 -> xpad 0; xh=1 -> xpad 65)
    if (tid < 24) {
        int bf = tid & 1, row = tid >> 1;           // row in [0,12)
        *(i32x4*)&lds[bf][(row*66 + (xh ? 65 : 0))*8] = i32x4{0,0,0,0};
    }

    f32x4 acc[2][2];
#pragma unroll
    for (int f = 0; f < 2; ++f)
#pragma unroll
        for (int nf = 0; nf < 2; ++nf) acc[f][nf] = f32x4{0.f,0.f,0.f,0.f};

    const unsigned short* aw0 = w2 + ((size_t)(co_base      + l15))*1024 + lhi*8;
    const unsigned short* aw1 = w2 + ((size_t)(co_base + 16 + l15))*1024 + lhi*8;

    bf16x8 afr0[18], afr1[18];
    i32x4 pre[3], preh;
    bool  pv[3], phv;

    // halo geometry (per-thread constants)
    const int h_row  = tid >> 1;                    // for tid<24
    const int h_side = tid & 1;
    const int h_zz   = z0 - 1 + (h_row >> 2);
    const int h_kg   = h_row & 3;
    const int h_x    = xh*64 - 1 + h_side*65;       // global x of halo col
    const bool h_ok  = (tid < 24) && ((unsigned)h_zz < 128u) && ((unsigned)h_x < 128u);
    const int h_xpad = h_side ? 65 : 0;

#define A_LOAD(DST, CI0)                                                       \
    {                                                                          \
        _Pragma("unroll")                                                      \
        for (int t = 0; t < 9; ++t) {                                          \
            DST[t*2]   = *(const bf16x8*)(aw0 + (size_t)t*131072 + (CI0));     \
            DST[t*2+1] = *(const bf16x8*)(aw1 + (size_t)t*131072 + (CI0));     \
        }                                                                      \
    }
// interior: 12 rows x 64 x -> 768 i32x4 = 3*256
#define B_LOAD(CI0)                                                            \
    {                                                                          \
        _Pragma("unroll")                                                      \
        for (int j = 0; j < 3; ++j) {                                          \
            int i  = tid + j*256;                                              \
            int kg = i & 3, x = (i >> 2) & 63, zr = i >> 8;                    \
            int zz = z0 - 1 + zr;                                              \
            pv[j] = ((unsigned)zz < 128u);                                     \
            if (pv[j])                                                         \
                pre[j] = *(const i32x4*)&bevin[((size_t)(zz*128 + xh*64 + x))*1024 + (CI0) + kg*8]; \
        }                                                                      \
        phv = h_ok;                                                            \
        if (phv)                                                               \
            preh = *(const i32x4*)&bevin[((size_t)(h_zz*128 + h_x))*1024 + (CI0) + h_kg*8]; \
    }
#define B_WRITE(BUF)                                                           \
    {                                                                          \
        _Pragma("unroll")                                                      \
        for (int j = 0; j < 3; ++j) {                                          \
            int i  = tid + j*256;                                              \
            int kg = i & 3, x = (i >> 2) & 63, zr = i >> 8;                    \
            if (pv[j])                                                         \
                *(i32x4*)&lds[BUF][(((zr*4 + kg)*66) + 1 + x)*8] = pre[j];     \
        }                                                                      \
        if (phv)                                                               \
            *(i32x4*)&lds[BUF][((h_zz - (z0-1))*4*66 + h_kg*66 + h_xpad)*8] = preh; \
    }
#define COMPUTE(BUF, AFR)                                                      \
    {                                                                          \
        _Pragma("unroll")                                                      \
        for (int dz = 0; dz < 3; ++dz) {                                       \
            if ((unsigned)(z0 - 1 + dz) < 128u) {                              \
                _Pragma("unroll")                                              \
                for (int dx = 0; dx < 3; ++dx) {                               \
                    bf16x8 a0 = AFR[(dz*3+dx)*2];                              \
                    bf16x8 a1 = AFR[(dz*3+dx)*2+1];                            \
                    _Pragma("unroll")                                          \
                    for (int nf = 0; nf < 2; ++nf) {                           \
                        int xp = xw*32 + nf*16 + l15 + dx;                     \
                        bf16x8 bfr = *(const bf16x8*)&lds[BUF][(((dz*4 + lhi)*66) + xp)*8]; \
                        acc[0][nf] = __builtin_amdgcn_mfma_f32_16x16x32_bf16(a0, bfr, acc[0][nf], 0, 0, 0); \
                        acc[1][nf] = __builtin_amdgcn_mfma_f32_16x16x32_bf16(a1, bfr, acc[1][nf], 0, 0, 0); \
                    }                                                          \
                }                                                              \
            }                                                                  \
        }                                                                      \
    }

    // prologue: chunk 0 -> buf0 / afr0
    B_LOAD(0);
    A_LOAD(afr0, 0);
    __syncthreads();     // pad zero-fill visible
    B_WRITE(0);
    __syncthreads();

    for (int cc = 0; cc < 16; ++cc) {
        const int ci0 = cc*64;
        // --- chunk cc*2 : compute buf0/afr0, prefetch chunk cc*2+1 -> buf1/afr1
        B_LOAD(ci0 + 32);
        A_LOAD(afr1, ci0 + 32);
        COMPUTE(0, afr0);
        B_WRITE(1);
        __syncthreads();
        // --- chunk cc*2+1 : compute buf1/afr1, prefetch chunk cc*2+2 -> buf0/afr0
        if (cc < 15) {
            B_LOAD(ci0 + 64);
            A_LOAD(afr0, ci0 + 64);
        }
        COMPUTE(1, afr1);
        if (cc < 15) {
            B_WRITE(0);
            __syncthreads();
        }
    }

    // epilogue: D row=(lhi*4+r) -> co, col=l15 -> x
#pragma unroll
    for (int f = 0; f < 2; ++f)
#pragma unroll
        for (int nf = 0; nf < 2; ++nf)
#pragma unroll
            for (int r = 0; r < 4; ++r) {
                int co = co_base + f*16 + lhi*4 + r;
                out[(size_t)co*16384 + z0*128 + xh*64 + xw*32 + nf*16 + l15] = acc[f][nf][r];
            }
#undef A_LOAD
#undef B_LOAD
#undef B_WRITE
#undef COMPUTE
}

// ---------------- instance-norm stats ----------------
__global__ __launch_bounds__(256) void k_instnorm_stats(const float* __restrict__ out,
                                                        float* __restrict__ stats) {
    __shared__ float r1[256], r2[256];
    int co = blockIdx.x, tid = threadIdx.x;
    const float* p = out + (size_t)co*16384;
    float s1 = 0.0f, s2 = 0.0f;
    for (int i = tid; i < 16384; i += 256) { float v = p[i]; s1 += v; s2 += v*v; }
    r1[tid] = s1; r2[tid] = s2;
    __syncthreads();
    for (int off = 128; off > 0; off >>= 1) {
        if (tid < off) { r1[tid] += r1[tid+off]; r2[tid] += r2[tid+off]; }
        __syncthreads();
    }
    if (tid == 0) {
        float mean = r1[0] * (1.0f/16384.0f);
        float var  = r2[0] * (1.0f/16384.0f) - mean*mean;
        stats[co*2]   = mean;
        stats[co*2+1] = rsqrtf(var + 1e-5f);
    }
}

// ---------------- normalize + exact GELU (in place) ----------------
__global__ __launch_bounds__(256) void k_gelu(float* __restrict__ out,
                                              const float* __restrict__ stats) {
    int i = blockIdx.x*256 + threadIdx.x;
    int co = i >> 14;
    float v = out[i];
    float r = (v - stats[co*2]) * stats[co*2+1];
    out[i] = 0.5f * r * (1.0f + erff(r * 0.70710678118654752f));
}

extern "C" void kernel_launch(void* const* d_in, const int* in_sizes, int n_in,
                              void* d_out, int out_size, void* d_ws, size_t ws_size,
                              hipStream_t stream) {
    const float* cam_feat = (const float*)d_in[0];
    const float* intrins  = (const float*)d_in[1];
    const float* rots     = (const float*)d_in[2];
    const float* trans    = (const float*)d_in[3];
    const float* conv_w   = (const float*)d_in[4];
    float* out = (float*)d_out;
    float* ws  = (float*)d_ws;

    float* mats  = ws;                                          // 160 f
    float* uv    = ws + 160;                                    // NVOX*12 f
    unsigned short* featT = (unsigned short*)(uv + (size_t)NVOX*12);   // 4,300,800 bf16
    unsigned short* bevin = featT + (size_t)SNUM*HW*CNUM;       // 16,777,216 bf16
    unsigned short* w2    = bevin + (size_t)16384*1024;         // 1,179,648 bf16
    float* stats = (float*)(w2 + 9*128*1024);                   // 256 f
    // total ~50.8 MB

    hipLaunchKernelGGL(k_setup, dim3(1), dim3(64), 0, stream, intrins, rots, trans, mats);
    hipLaunchKernelGGL(k_tfeat, dim3(HW/32, CNUM/32, SNUM), dim3(32,8), 0, stream, cam_feat, featT);
    hipLaunchKernelGGL(k_geo, dim3(NVOX/256), dim3(256), 0, stream, mats, uv);
    hipLaunchKernelGGL(k_wprep, dim3((9*128*1024 + 255)/256), dim3(256), 0, stream, conv_w, w2);
    hipLaunchKernelGGL(k_sample, dim3(8192), dim3(256), 0, stream, featT, uv, bevin);
    hipLaunchKernelGGL(k_conv_mfma, dim3(128, 4), dim3(256), 0, stream, bevin, w2, out);
    hipLaunchKernelGGL(k_instnorm_stats, dim3(128), dim3(256), 0, stream, out, stats);
    hipLaunchKernelGGL(k_gelu, dim3(8192), dim3(256), 0, stream, out, stats);
}

// Round 6
// 153.867 us; speedup vs baseline: 1.4215x; 1.3682x over previous
//
#include <hip/hip_runtime.h>
#include <cmath>

// ---------------- problem constants ----------------
#define SNUM 6
#define CNUM 128
#define HF 56
#define WF 100
#define HW (HF*WF)          // 5600
#define ZN 128
#define YN 8
#define XN 128
#define NVOX (ZN*YN*XN)     // 131072

typedef __attribute__((ext_vector_type(8))) short bf16x8;
typedef __attribute__((ext_vector_type(4))) float f32x4;
typedef __attribute__((ext_vector_type(4))) int   i32x4;

__device__ __forceinline__ unsigned short f2bf(float f) {
    unsigned u = __builtin_bit_cast(unsigned, f);
    unsigned r = (u + 0x7FFFu + ((u >> 16) & 1u)) >> 16;   // RNE
    return (unsigned short)r;
}
__device__ __forceinline__ float bf2f(unsigned short h) {
    unsigned u = (unsigned)h << 16;
    return __builtin_bit_cast(float, u);
}

// ---------------- setup: per-camera matrices ----------------
__global__ void k_setup(const float* __restrict__ intrins,
                        const float* __restrict__ rots,
                        const float* __restrict__ trans,
                        float* __restrict__ mats) {
    int s = threadIdx.x;
    if (s >= SNUM) return;
    float R0[9], Rs[9], t0[3], ts[3];
    for (int i = 0; i < 9; ++i) { R0[i] = rots[i]; Rs[i] = rots[s*9 + i]; }
    for (int i = 0; i < 3; ++i) { t0[i] = trans[i]; ts[i] = trans[s*3 + i]; }
    float M[3][4];
    float d0 = t0[0]-ts[0], d1 = t0[1]-ts[1], d2 = t0[2]-ts[2];
    for (int i = 0; i < 3; ++i) {
        for (int j = 0; j < 3; ++j)
            M[i][j] = Rs[0*3+i]*R0[0*3+j] + Rs[1*3+i]*R0[1*3+j] + Rs[2*3+i]*R0[2*3+j];
        M[i][3] = Rs[0*3+i]*d0 + Rs[1*3+i]*d1 + Rs[2*3+i]*d2;
    }
    const float sx = (float)WF/800.0f, sy = (float)HF/448.0f;
    float fx = intrins[s*16 + 0]*sx, fy = intrins[s*16 + 5]*sy;
    float cx = intrins[s*16 + 2]*sx, cy = intrins[s*16 + 6]*sy;
    float* o = mats + s*24;
    for (int j = 0; j < 4; ++j) {
        o[0*4+j]      = M[0][j];
        o[1*4+j]      = M[1][j];
        o[2*4+j]      = M[2][j];
        o[12 + 0*4+j] = fx*M[0][j] + cx*M[2][j];
        o[12 + 1*4+j] = fy*M[1][j] + cy*M[2][j];
        o[12 + 2*4+j] = M[2][j];
    }
}

// ---------------- transpose cam_feat (S,C,HW) f32 -> featT (S,HW,C) bf16 -------
__global__ __launch_bounds__(256) void k_tfeat(const float* __restrict__ cf,
                                               unsigned short* __restrict__ featT) {
    __shared__ float t[32][33];
    int s = blockIdx.z;
    int p0 = blockIdx.x * 32, c0 = blockIdx.y * 32;
    int tx = threadIdx.x, ty = threadIdx.y;   // 32 x 8
#pragma unroll
    for (int k = 0; k < 4; ++k) {
        int r = ty + k*8;
        t[r][tx] = cf[((size_t)s*CNUM + c0 + r)*HW + p0 + tx];
    }
    __syncthreads();
#pragma unroll
    for (int k = 0; k < 4; ++k) {
        int r = ty + k*8;
        featT[((size_t)s*HW + p0 + r)*CNUM + c0 + tx] = f2bf(t[tx][r]);
    }
}

// ---------------- per-voxel projection -> (ux,uy) per camera ----------------
__global__ __launch_bounds__(256) void k_geo(const float* __restrict__ mats,
                                             float* __restrict__ uv) {
#pragma clang fp contract(off)
    int n = blockIdx.x * 256 + threadIdx.x;
    int zi = n >> 10, yi = (n >> 7) & 7, xi = n & 127;
    float xr = -49.609375f + (float)xi * 0.78125f;
    float yr = (-4.9f + 0.625f) + (float)yi * 1.25f;
    float zr = -49.609375f + (float)zi * 0.78125f;
#pragma unroll
    for (int s = 0; s < SNUM; ++s) {
        const float* m = mats + s*24;
        float zc = m[8]*xr  + m[9]*yr  + m[10]*zr + m[11];
        float ph = m[12]*xr + m[13]*yr + m[14]*zr + m[15];
        float qh = m[16]*xr + m[17]*yr + m[18]*zr + m[19];
        float denom = fmaxf(zc, 1e-6f);
        float px = ph / denom, py = qh / denom;
        bool valid = (px > -0.5f) & (px < (float)WF - 0.5f) &
                     (py > -0.5f) & (py < (float)HF - 0.5f) & (zc > 0.0f);
        float ux = -10000.0f, uy = -10000.0f;
        if (valid) {
            float gx = 2.0f*px/((float)WF - 1.0f) - 1.0f;
            float gy = 2.0f*py/((float)HF - 1.0f) - 1.0f;
            gx = fminf(fmaxf(gx, -2.0f), 2.0f);
            gy = fminf(fmaxf(gy, -2.0f), 2.0f);
            ux = ((gx + 1.0f)*(float)WF - 1.0f)*0.5f;
            uy = ((gy + 1.0f)*(float)HF - 1.0f)*0.5f;
        }
        uv[(n*SNUM + s)*2]     = ux;
        uv[(n*SNUM + s)*2 + 1] = uy;
    }
}

// ---------------- bilinear sample + masked camera mean -> bevin bf16 [z][x][ci] ----
__global__ __launch_bounds__(256) void k_sample(const unsigned short* __restrict__ featT,
                                                const float* __restrict__ uv,
                                                unsigned short* __restrict__ bevin) {
#pragma clang fp contract(off)
    __shared__ float xch[16][132];        // [vs = y*2+xs][c]
    const int tid = threadIdx.x;
    const int b = blockIdx.x;             // 8192 = 128 z * 64 x-pairs
    const int z = b >> 6, x0 = (b & 63) * 2;
    const int cl = tid & 15, vs = tid >> 4;
    const int y = vs >> 1, xs = vs & 1;
    const int n = z*1024 + y*128 + x0 + xs;
    const bf16x8 zz8 = {0,0,0,0,0,0,0,0};
    float sum[8], cnt[8];
#pragma unroll
    for (int k = 0; k < 8; ++k) { sum[k] = 0.0f; cnt[k] = 0.0f; }
    for (int s = 0; s < SNUM; ++s) {
        float2 u = ((const float2*)uv)[n*SNUM + s];
        if (u.x < -999.0f) continue;
        float x0f = floorf(u.x), y0f = floorf(u.y);
        float wx = u.x - x0f, wy = u.y - y0f;
        int ix = (int)x0f, iy = (int)y0f;
        float w00 = (1.0f-wx)*(1.0f-wy), w10 = wx*(1.0f-wy);
        float w01 = (1.0f-wx)*wy,        w11 = wx*wy;
        bool bx0 = (ix >= 0) & (ix < WF);
        bool bx1 = (ix >= -1) & (ix < WF-1);
        bool by0 = (iy >= 0) & (iy < HF);
        bool by1 = (iy >= -1) & (iy < HF-1);
        bool c00 = bx0 & by0, c10 = bx1 & by0, c01 = bx0 & by1, c11 = bx1 & by1;
        const unsigned short* fb = featT + (size_t)s * (HW*CNUM) + cl*8;
        long r0 = (long)(iy*WF + ix) * CNUM;
        bf16x8 v00 = c00 ? *(const bf16x8*)(fb + r0)                 : zz8;
        bf16x8 v10 = c10 ? *(const bf16x8*)(fb + r0 + CNUM)          : zz8;
        bf16x8 v01 = c01 ? *(const bf16x8*)(fb + r0 + WF*CNUM)       : zz8;
        bf16x8 v11 = c11 ? *(const bf16x8*)(fb + r0 + WF*CNUM + CNUM): zz8;
#pragma unroll
        for (int k = 0; k < 8; ++k) {
            float v = 0.0f;
            v = v + w00 * bf2f((unsigned short)v00[k]);
            v = v + w10 * bf2f((unsigned short)v10[k]);
            v = v + w01 * bf2f((unsigned short)v01[k]);
            v = v + w11 * bf2f((unsigned short)v11[k]);
            sum[k] += v;
            cnt[k] += (v != 0.0f) ? 1.0f : 0.0f;
        }
    }
#pragma unroll
    for (int k = 0; k < 8; ++k)
        xch[vs][cl*8 + k] = sum[k] / (1e-6f + cnt[k]);
    __syncthreads();
    // pack to bf16: element e = c*8+y at bevin[(z*128 + x0+xs)*1024 + e]
#pragma unroll
    for (int j = 0; j < 4; ++j) {
        int m = tid + j*256;              // uint index in [0,1024)
        int xs2 = m >> 9;
        int r = m & 511;                  // elements 2r, 2r+1
        int c = (2*r) >> 3, y0 = (2*r) & 7;
        float v0 = xch[y0*2 + xs2][c];
        float v1 = xch[(y0+1)*2 + xs2][c];
        unsigned pk = (unsigned)f2bf(v0) | ((unsigned)f2bf(v1) << 16);
        ((unsigned*)bevin)[(size_t)(z*128 + x0 + xs2)*512 + r] = pk;
    }
}

// ---------------- weight prep: conv_w [co][ci][3][3] f32 -> w2 [tap][co][ci] bf16 ----
__global__ __launch_bounds__(256) void k_wprep(const float* __restrict__ w,
                                               unsigned short* __restrict__ w2) {
    int i = blockIdx.x*256 + threadIdx.x;     // over 9*128*1024
    if (i >= 9*128*1024) return;
    int ci = i & 1023; int rest = i >> 10; int co = rest & 127; int tap = rest >> 7;
    w2[i] = f2bf(w[((size_t)co*1024 + ci)*9 + tap]);
}

// ---------------- MFMA implicit-GEMM conv 3x3 ----------------
// grid (128 z, coh*2+xh) = 512 blocks of 128 thr -> 2 independent blocks/CU.
// block = 2 waves = 64co x 64x; wave tile 32co x 64x (balanced A-L2/B-LDS traffic).
// A (weights) register-double-buffered; B (activations) LDS double-buffered;
// one barrier per ci-chunk; the 2 co-resident blocks interleave phases.
__global__ __launch_bounds__(128, 1) void k_conv_mfma(
        const unsigned short* __restrict__ bevin,   // [z][x][1024] bf16
        const unsigned short* __restrict__ w2,      // [tap][co][1024] bf16
        float* __restrict__ out) {
    __shared__ unsigned short lds[2][12*66*8];      // [buf][(zr*4+kg)*66 + xpad][8ci]
    const int tid  = threadIdx.x;                   // 0..127
    const int z0   = blockIdx.x;
    const int coh  = blockIdx.y >> 1;               // co half: 0,1
    const int xh   = blockIdx.y & 1;                // x half: 0,1
    const int lane = tid & 63, wr = tid >> 6;       // 2 waves = 2 co-rows
    const int co_base = coh*64 + wr*32;
    const int l15 = lane & 15, lhi = lane >> 4;

    // zero the out-of-range halo column once (xh=0 -> xpad 0; xh=1 -> xpad 65)
    if (tid < 24) {
        int bf = tid & 1, row = tid >> 1;           // row in [0,12)
        *(i32x4*)&lds[bf][(row*66 + (xh ? 65 : 0))*8] = i32x4{0,0,0,0};
    }

    f32x4 acc[2][4];
#pragma unroll
    for (int f = 0; f < 2; ++f)
#pragma unroll
        for (int nf = 0; nf < 4; ++nf) acc[f][nf] = f32x4{0.f,0.f,0.f,0.f};

    const unsigned short* aw0 = w2 + ((size_t)(co_base      + l15))*1024 + lhi*8;
    const unsigned short* aw1 = w2 + ((size_t)(co_base + 16 + l15))*1024 + lhi*8;

    bf16x8 afr0[18], afr1[18];
    i32x4 pre[6], preh;
    bool  pv[6], phv;

    // halo geometry (per-thread constants; threads 0..23)
    const int h_row  = tid >> 1;
    const int h_side = tid & 1;
    const int h_zz   = z0 - 1 + (h_row >> 2);
    const int h_kg   = h_row & 3;
    const int h_x    = xh*64 - 1 + h_side*65;       // global x of halo col
    const bool h_ok  = (tid < 24) && ((unsigned)h_zz < 128u) && ((unsigned)h_x < 128u);
    const int h_xpad = h_side ? 65 : 0;

#define A_LOAD(DST, CI0)                                                       \
    {                                                                          \
        _Pragma("unroll")                                                      \
        for (int t = 0; t < 9; ++t) {                                          \
            DST[t*2]   = *(const bf16x8*)(aw0 + (size_t)t*131072 + (CI0));     \
            DST[t*2+1] = *(const bf16x8*)(aw1 + (size_t)t*131072 + (CI0));     \
        }                                                                      \
    }
// interior: 12 kg-rows x 64 x -> 768 i32x4 = 6*128
#define B_LOAD(CI0)                                                            \
    {                                                                          \
        _Pragma("unroll")                                                      \
        for (int j = 0; j < 6; ++j) {                                          \
            int i  = tid + j*128;                                              \
            int kg = i & 3, x = (i >> 2) & 63, zr = i >> 8;                    \
            int zz = z0 - 1 + zr;                                              \
            pv[j] = ((unsigned)zz < 128u);                                     \
            if (pv[j])                                                         \
                pre[j] = *(const i32x4*)&bevin[((size_t)(zz*128 + xh*64 + x))*1024 + (CI0) + kg*8]; \
        }                                                                      \
        phv = h_ok;                                                            \
        if (phv)                                                               \
            preh = *(const i32x4*)&bevin[((size_t)(h_zz*128 + h_x))*1024 + (CI0) + h_kg*8]; \
    }
#define B_WRITE(BUF)                                                           \
    {                                                                          \
        _Pragma("unroll")                                                      \
        for (int j = 0; j < 6; ++j) {                                          \
            int i  = tid + j*128;                                              \
            int kg = i & 3, x = (i >> 2) & 63, zr = i >> 8;                    \
            if (pv[j])                                                         \
                *(i32x4*)&lds[BUF][(((zr*4 + kg)*66) + 1 + x)*8] = pre[j];     \
        }                                                                      \
        if (phv)                                                               \
            *(i32x4*)&lds[BUF][((h_zz - (z0-1))*4*66 + h_kg*66 + h_xpad)*8] = preh; \
    }
#define COMPUTE(BUF, AFR)                                                      \
    {                                                                          \
        _Pragma("unroll")                                                      \
        for (int dz = 0; dz < 3; ++dz) {                                       \
            if ((unsigned)(z0 - 1 + dz) < 128u) {                              \
                _Pragma("unroll")                                              \
                for (int dx = 0; dx < 3; ++dx) {                               \
                    bf16x8 a0 = AFR[(dz*3+dx)*2];                              \
                    bf16x8 a1 = AFR[(dz*3+dx)*2+1];                            \
                    _Pragma("unroll")                                          \
                    for (int nf = 0; nf < 4; ++nf) {                           \
                        int xp = nf*16 + l15 + dx;                             \
                        bf16x8 bfr = *(const bf16x8*)&lds[BUF][(((dz*4 + lhi)*66) + xp)*8]; \
                        acc[0][nf] = __builtin_amdgcn_mfma_f32_16x16x32_bf16(a0, bfr, acc[0][nf], 0, 0, 0); \
                        acc[1][nf] = __builtin_amdgcn_mfma_f32_16x16x32_bf16(a1, bfr, acc[1][nf], 0, 0, 0); \
                    }                                                          \
                }                                                              \
            }                                                                  \
        }                                                                      \
    }

    // prologue: chunk 0 -> buf0 / afr0
    B_LOAD(0);
    A_LOAD(afr0, 0);
    __syncthreads();     // pad zero-fill visible
    B_WRITE(0);
    __syncthreads();

    for (int cc = 0; cc < 16; ++cc) {
        const int ci0 = cc*64;
        // --- chunk cc*2 : compute buf0/afr0, prefetch chunk cc*2+1 -> buf1/afr1
        B_LOAD(ci0 + 32);
        A_LOAD(afr1, ci0 + 32);
        COMPUTE(0, afr0);
        B_WRITE(1);
        __syncthreads();
        // --- chunk cc*2+1 : compute buf1/afr1, prefetch chunk cc*2+2 -> buf0/afr0
        if (cc < 15) {
            B_LOAD(ci0 + 64);
            A_LOAD(afr0, ci0 + 64);
        }
        COMPUTE(1, afr1);
        if (cc < 15) {
            B_WRITE(0);
            __syncthreads();
        }
    }

    // epilogue: D row=(lhi*4+r) -> co, col=l15 -> x
#pragma unroll
    for (int f = 0; f < 2; ++f)
#pragma unroll
        for (int nf = 0; nf < 4; ++nf)
#pragma unroll
            for (int r = 0; r < 4; ++r) {
                int co = co_base + f*16 + lhi*4 + r;
                out[(size_t)co*16384 + z0*128 + xh*64 + nf*16 + l15] = acc[f][nf][r];
            }
#undef A_LOAD
#undef B_LOAD
#undef B_WRITE
#undef COMPUTE
}

// ---------------- instance-norm stats ----------------
__global__ __launch_bounds__(256) void k_instnorm_stats(const float* __restrict__ out,
                                                        float* __restrict__ stats) {
    __shared__ float r1[256], r2[256];
    int co = blockIdx.x, tid = threadIdx.x;
    const float* p = out + (size_t)co*16384;
    float s1 = 0.0f, s2 = 0.0f;
    for (int i = tid; i < 16384; i += 256) { float v = p[i]; s1 += v; s2 += v*v; }
    r1[tid] = s1; r2[tid] = s2;
    __syncthreads();
    for (int off = 128; off > 0; off >>= 1) {
        if (tid < off) { r1[tid] += r1[tid+off]; r2[tid] += r2[tid+off]; }
        __syncthreads();
    }
    if (tid == 0) {
        float mean = r1[0] * (1.0f/16384.0f);
        float var  = r2[0] * (1.0f/16384.0f) - mean*mean;
        stats[co*2]   = mean;
        stats[co*2+1] = rsqrtf(var + 1e-5f);
    }
}

// ---------------- normalize + exact GELU (in place) ----------------
__global__ __launch_bounds__(256) void k_gelu(float* __restrict__ out,
                                              const float* __restrict__ stats) {
    int i = blockIdx.x*256 + threadIdx.x;
    int co = i >> 14;
    float v = out[i];
    float r = (v - stats[co*2]) * stats[co*2+1];
    out[i] = 0.5f * r * (1.0f + erff(r * 0.70710678118654752f));
}

extern "C" void kernel_launch(void* const* d_in, const int* in_sizes, int n_in,
                              void* d_out, int out_size, void* d_ws, size_t ws_size,
                              hipStream_t stream) {
    const float* cam_feat = (const float*)d_in[0];
    const float* intrins  = (const float*)d_in[1];
    const float* rots     = (const float*)d_in[2];
    const float* trans    = (const float*)d_in[3];
    const float* conv_w   = (const float*)d_in[4];
    float* out = (float*)d_out;
    float* ws  = (float*)d_ws;

    float* mats  = ws;                                          // 160 f
    float* uv    = ws + 160;                                    // NVOX*12 f
    unsigned short* featT = (unsigned short*)(uv + (size_t)NVOX*12);   // 4,300,800 bf16
    unsigned short* bevin = featT + (size_t)SNUM*HW*CNUM;       // 16,777,216 bf16
    unsigned short* w2    = bevin + (size_t)16384*1024;         // 1,179,648 bf16
    float* stats = (float*)(w2 + 9*128*1024);                   // 256 f
    // total ~50.8 MB

    hipLaunchKernelGGL(k_setup, dim3(1), dim3(64), 0, stream, intrins, rots, trans, mats);
    hipLaunchKernelGGL(k_tfeat, dim3(HW/32, CNUM/32, SNUM), dim3(32,8), 0, stream, cam_feat, featT);
    hipLaunchKernelGGL(k_geo, dim3(NVOX/256), dim3(256), 0, stream, mats, uv);
    hipLaunchKernelGGL(k_wprep, dim3((9*128*1024 + 255)/256), dim3(256), 0, stream, conv_w, w2);
    hipLaunchKernelGGL(k_sample, dim3(8192), dim3(256), 0, stream, featT, uv, bevin);
    hipLaunchKernelGGL(k_conv_mfma, dim3(128, 4), dim3(128), 0, stream, bevin, w2, out);
    hipLaunchKernelGGL(k_instnorm_stats, dim3(128), dim3(256), 0, stream, out, stats);
    hipLaunchKernelGGL(k_gelu, dim3(8192), dim3(256), 0, stream, out, stats);
}